// Round 14
// baseline (921.319 us; speedup 1.0000x reference)
//
#include <hip/hip_runtime.h>
#include <hip/hip_bf16.h>

// B=16, M=4096, D=64, K=1024. fp32 in / fp32 out.
// Output: [z_q_st (N*D) | indices (N) | loss (1)], fp32.
//
// R13 post-mortem: dynamic xv[p*16+..] indexing -> scratch spill (WRITE 82MB,
// VALUBusy 3.7%). Also: LDS return-BW wall = N*K*D*4B / R_rowblock.
// R14: quad-D-split (lane p holds comps [16p,16p+16)) + R=8 rows/lane in
// 128 VGPRs -> LDS traffic /8 (~31us), VALU-bound scan ~90us. All register
// arrays statically indexed (full unroll). fp32 screen + margin + exact fp64
// wave-cooperative rescan (R12-proven semantics, x via quad shfl).
#define D_     64
#define K_     1024
#define N_     65536
#define TK     64             // codes per LDS tile (16 KB, unpadded: 2-way=free)
#define TPB    64             // one wave per block
#define R_     8              // rows per quad
#define RPB    128            // 16 quads * 8 rows
#define NBLK   (N_ / RPB)     // 512 blocks
#define MARGIN 1.0e-2f        // screen err ~1e-4 abs; 100x safety

// ---------------------------------------------------------------------------
// Kernel A: ||e_k||^2 exact fp64 + fp32 copy for the screen
// ---------------------------------------------------------------------------
__global__ __launch_bounds__(256) void vq_norms(const float* __restrict__ embed,
                                                double* __restrict__ n64,
                                                float* __restrict__ n32) {
    const int k = blockIdx.x * 256 + threadIdx.x;
    const float4* e4 = (const float4*)(embed + (size_t)k * D_);
    double acc = 0.0;
#pragma unroll
    for (int q = 0; q < 16; ++q) {
        const float4 e = e4[q];
        acc = fma((double)e.x, (double)e.x, acc);
        acc = fma((double)e.y, (double)e.y, acc);
        acc = fma((double)e.z, (double)e.z, acc);
        acc = fma((double)e.w, (double)e.w, acc);
    }
    n64[k] = acc;
    n32[k] = (float)acc;
}

// ---------------------------------------------------------------------------
// Kernel B: 1 wave/block, 128 rows/block. Quad lane p holds comps
// [16p,16p+16) of 8 rows. fp32 screen, quad shfl-reduce, top-2 margin,
// exact fp64 rescan for flagged rows.
// ---------------------------------------------------------------------------
__global__ __launch_bounds__(TPB, 2) void vq_main(const float* __restrict__ z_e,
                                                  const float* __restrict__ embed,
                                                  const float* __restrict__ n32,
                                                  const double* __restrict__ n64,
                                                  float* __restrict__ out,
                                                  float* __restrict__ partials) {
    __shared__ float lds_e[TK * D_];   // 16 KB code tile
    __shared__ float lds_n[TK];

    const int tid  = threadIdx.x;      // 0..63
    const int p    = tid & 3;          // comp-quarter
    const int g    = tid >> 2;         // quad id 0..15
    const int row0 = blockIdx.x * RPB + g * R_;

    // xv[j][q*4+w] = z_e[row0+j][16p + q*4 + w]  (all indices static-unrolled)
    float xv[R_][16];
#pragma unroll
    for (int j = 0; j < R_; ++j) {
        const float4* xg = (const float4*)(z_e + (size_t)(row0 + j) * D_ + p * 16);
#pragma unroll
        for (int q = 0; q < 4; ++q) {
            const float4 x = xg[q];
            xv[j][q * 4 + 0] = x.x; xv[j][q * 4 + 1] = x.y;
            xv[j][q * 4 + 2] = x.z; xv[j][q * 4 + 3] = x.w;
        }
    }

    float b1[R_], b2[R_];
    int   i1[R_];
#pragma unroll
    for (int j = 0; j < R_; ++j) { b1[j] = 3.4e38f; b2[j] = 3.4e38f; i1[j] = 0; }

    for (int kt = 0; kt < K_; kt += TK) {
        __syncthreads();
        {   // stage TK codes: 1024 float4, 16 per lane, coalesced
            const float4* esrc = (const float4*)(embed + (size_t)kt * D_);
            float4* ld4 = (float4*)lds_e;
#pragma unroll
            for (int i = 0; i < 16; ++i) ld4[tid + i * 64] = esrc[tid + i * 64];
            lds_n[tid] = n32[kt + tid];   // TPB == TK
        }
        __syncthreads();

        for (int kk = 0; kk < TK; ++kk) {
            const float4* ev = (const float4*)(lds_e + kk * D_ + p * 16);
            const float4 e0 = ev[0], e1 = ev[1], e2 = ev[2], e3 = ev[3];
            const float  nk = lds_n[kk];
            const int    c  = kt + kk;
#pragma unroll
            for (int j = 0; j < R_; ++j) {
                float a = 0.f;
                a = fmaf(xv[j][0],  e0.x, a); a = fmaf(xv[j][1],  e0.y, a);
                a = fmaf(xv[j][2],  e0.z, a); a = fmaf(xv[j][3],  e0.w, a);
                a = fmaf(xv[j][4],  e1.x, a); a = fmaf(xv[j][5],  e1.y, a);
                a = fmaf(xv[j][6],  e1.z, a); a = fmaf(xv[j][7],  e1.w, a);
                a = fmaf(xv[j][8],  e2.x, a); a = fmaf(xv[j][9],  e2.y, a);
                a = fmaf(xv[j][10], e2.z, a); a = fmaf(xv[j][11], e2.w, a);
                a = fmaf(xv[j][12], e3.x, a); a = fmaf(xv[j][13], e3.y, a);
                a = fmaf(xv[j][14], e3.z, a); a = fmaf(xv[j][15], e3.w, a);
                // quad reduce (DPP): full dot lands in all 4 quad lanes
                a += __shfl_xor(a, 1);
                a += __shfl_xor(a, 2);
                const float s  = fmaf(-2.0f, a, nk);
                const bool  lt = s < b1[j];
                // b2 = med3(s,b1,b2) branch-free; then b1/i1 (old-b1 order!)
                b2[j] = fminf(b2[j], fmaxf(b1[j], s));
                i1[j] = lt ? c : i1[j];
                b1[j] = fminf(b1[j], s);
            }
        }
    }

    // Flagged rows: wave-cooperative EXACT fp64 rescan (rare).
#pragma unroll
    for (int j = 0; j < R_; ++j) {
        unsigned long long mask = __ballot((p == 0) && (b2[j] - b1[j] < MARGIN));
        while (mask) {
            const int src = __ffsll((long long)mask) - 1;   // leader lane of quad
            mask &= mask - 1;
            double bs = 1.0e300; int bi = 1 << 30;
            for (int c0 = 0; c0 < K_; c0 += 64) {
                const int c = c0 + tid;
                const float* ep = embed + (size_t)c * D_;
                double dot = 0.0;
#pragma unroll
                for (int jj = 0; jj < D_; ++jj) {
                    // x[jj] lives in quad lane src+(jj>>4), reg xv[j][jj&15]
                    const float xj = __shfl(xv[j][jj & 15], src + (jj >> 4));
                    dot = fma((double)xj, (double)ep[jj], dot);
                }
                const double s = fma(-2.0, dot, n64[c]);
                if (s < bs) { bs = s; bi = c; }
            }
#pragma unroll
            for (int off = 32; off > 0; off >>= 1) {        // (s,idx) lex-min
                const double so = __shfl_xor(bs, off);
                const int    io = __shfl_xor(bi, off);
                if (so < bs || (so == bs && io < bi)) { bs = so; bi = io; }
            }
            if (tid == src) i1[j] = bi;
        }
        i1[j] = __shfl(i1[j], tid & ~3);   // re-sync quad copies from leader
    }

    // Epilogue: lane p writes comps [16p,16p+16) of each row.
    float sq = 0.f;
#pragma unroll
    for (int j = 0; j < R_; ++j) {
        const int bidx = i1[j] & (K_ - 1);
        const float4* eg = (const float4*)(embed + (size_t)bidx * D_ + p * 16);
        float4*       o0 = (float4*)(out + (size_t)(row0 + j) * D_ + p * 16);
#pragma unroll
        for (int q = 0; q < 4; ++q) {
            const float4 e = eg[q];
            const float d0 = e.x - xv[j][q * 4 + 0];
            const float d1 = e.y - xv[j][q * 4 + 1];
            const float d2 = e.z - xv[j][q * 4 + 2];
            const float d3 = e.w - xv[j][q * 4 + 3];
            sq = fmaf(d0, d0, sq); sq = fmaf(d1, d1, sq);
            sq = fmaf(d2, d2, sq); sq = fmaf(d3, d3, sq);
            float4 o;
            o.x = xv[j][q * 4 + 0] + d0;
            o.y = xv[j][q * 4 + 1] + d1;
            o.z = xv[j][q * 4 + 2] + d2;
            o.w = xv[j][q * 4 + 3] + d3;
            o0[q] = o;
        }
        if (p == 0) out[(size_t)N_ * D_ + row0 + j] = (float)bidx;
    }

    // Wave loss reduction -> one partial per block
#pragma unroll
    for (int off = 32; off > 0; off >>= 1) sq += __shfl_down(sq, off);
    if (tid == 0) partials[blockIdx.x] = sq;
}

// ---------------------------------------------------------------------------
// Kernel C: reduce NBLK partials -> vq_loss = 1.25 * mean(sqdiff), fp32
// ---------------------------------------------------------------------------
__global__ __launch_bounds__(256) void vq_loss_final(const float* __restrict__ partials,
                                                     float* __restrict__ out) {
    __shared__ float red[256];
    const int tid = threadIdx.x;
    float s = 0.f;
#pragma unroll
    for (int i = 0; i < NBLK / 256; ++i) s += partials[tid + i * 256];
    red[tid] = s;
    __syncthreads();
#pragma unroll
    for (int w = 128; w > 0; w >>= 1) {
        if (tid < w) red[tid] += red[tid + w];
        __syncthreads();
    }
    if (tid == 0)
        out[(size_t)N_ * D_ + N_] = 1.25f * red[0] / (float)((size_t)N_ * D_);
}

// ---------------------------------------------------------------------------
extern "C" void kernel_launch(void* const* d_in, const int* in_sizes, int n_in,
                              void* d_out, int out_size, void* d_ws, size_t ws_size,
                              hipStream_t stream) {
    const float* z_e;
    const float* embed;
    if (in_sizes[0] == N_ * D_) {
        z_e   = (const float*)d_in[0];
        embed = (const float*)d_in[1];
    } else {
        z_e   = (const float*)d_in[1];
        embed = (const float*)d_in[0];
    }
    float* out = (float*)d_out;

    double* n64      = (double*)d_ws;       // 8 KB
    float*  n32      = (float*)(n64 + K_);  // 4 KB
    float*  partials = n32 + K_;            // 2 KB

    vq_norms<<<K_ / 256, 256, 0, stream>>>(embed, n64, n32);
    vq_main<<<NBLK, TPB, 0, stream>>>(z_e, embed, n32, n64, out, partials);
    vq_loss_final<<<1, 256, 0, stream>>>(partials, out);
}